// Round 1
// baseline (1765.506 us; speedup 1.0000x reference)
//
#include <hip/hip_runtime.h>
#include <stdint.h>

#define DIM_TIME 100
#define DQ 228
#define DKV 356
#define KP 360   // padded kv K-dim (356 -> 360, zeros beyond)

__device__ __forceinline__ unsigned short bf16_bits(float f) {
    union { float f; uint32_t u; } c; c.f = f;
    uint32_t u = c.u;
    uint32_t r = (u + 0x7FFFu + ((u >> 16) & 1u)) >> 16;
    return (unsigned short)r;
}
__device__ __forceinline__ float bf16_to_f(unsigned short h) {
    union { uint32_t u; float f; } c; c.u = ((uint32_t)h) << 16; return c.f;
}

// ---- prep: transpose [wk;wv] -> Wt[360][256] (zeros for k>=356) ----
__global__ void prep_wt(const float* __restrict__ wk_w, const float* __restrict__ wv_w,
                        float* __restrict__ Wt) {
    int k = blockIdx.x;        // 0..359
    int n = threadIdx.x;       // 0..255
    float v = 0.f;
    if (k < DKV) v = (n < 128) ? wk_w[n * DKV + k] : wv_w[(n - 128) * DKV + k];
    Wt[k * 256 + n] = v;
}

// ---- prep: const_q[o] = wq_b[o] + sum_t cos(time_b[t]) * wq_w[o,128+t] ----
__global__ void prep_cq(const float* __restrict__ wq_w, const float* __restrict__ wq_b,
                        const float* __restrict__ time_b, float* __restrict__ cq) {
    int o = threadIdx.x; // 128
    float s = wq_b[o];
    for (int t = 0; t < DIM_TIME; ++t)
        s += cosf(time_b[t]) * wq_w[o * DQ + 128 + t];
    cq[o] = s;
}

// ---- Qd[d,o] = const_q[o] + dot(q_row, wq_w[o,0:128]) ----
__global__ __launch_bounds__(512) void qd_kernel(
        const float* __restrict__ src_feat, const int* __restrict__ src_idx,
        const float* __restrict__ wq_w, const float* __restrict__ cq,
        float* __restrict__ Qd, int D) {
    __shared__ float q_s[4][128];
    int tid = threadIdx.x;
    int r = tid >> 7, o = tid & 127;
    int d = blockIdx.x * 4 + r;
    q_s[r][o] = (d < D) ? src_feat[(size_t)src_idx[d] * 128 + o] : 0.f;
    __syncthreads();
    if (d < D) {
        float acc = cq[o];
        const float4* w4 = (const float4*)(wq_w + (size_t)o * DQ);
        const float4* q4 = (const float4*)q_s[r];
        #pragma unroll
        for (int c = 0; c < 32; ++c) {
            float4 w = w4[c], q = q4[c];
            acc += q.x * w.x + q.y * w.y + q.z * w.z + q.w * w.w;
        }
        Qd[(size_t)d * 128 + o] = acc;
    }
}

// ---- KV GEMM: C[e][0:128]=K, C[e][128:256]=V, stored bf16 ----
// BM=32 edges, BN=256 outputs, fp32 register tile 4x8 per thread.
__global__ __launch_bounds__(256) void kv_gemm(
        const float* __restrict__ src_feat, const int* __restrict__ src_idx,
        const float* __restrict__ edge_f, const float* __restrict__ edge_dt,
        const float* __restrict__ time_w, const float* __restrict__ time_b,
        const float* __restrict__ Wt,
        const float* __restrict__ wk_b, const float* __restrict__ wv_b,
        unsigned short* __restrict__ KVb, int D, int E) {
    __shared__ float A_s[32][368];   // 32 edges x padded 368 cols
    __shared__ float W_s[8][256];
    int tid = threadIdx.x;
    int e0 = blockIdx.x * 32;

    // build A tile: cols 0..127 = gathered node feat, 128..255 = edge feat
    for (int m = 0; m < 32; ++m) {
        int e = e0 + m;
        float v = 0.f;
        if (e < E) {
            v = (tid < 128) ? src_feat[(size_t)src_idx[D + e] * 128 + tid]
                            : edge_f[(size_t)e * 128 + (tid - 128)];
        }
        A_s[m][tid] = v;
    }
    // cols 256..367: time encoding (100 cos values, zeros beyond)
    for (int idx = tid; idx < 32 * 112; idx += 256) {
        int m = idx / 112, kk = idx - (idx / 112) * 112;
        int e = e0 + m;
        float v = 0.f;
        if (kk < DIM_TIME && e < E)
            v = cosf(edge_dt[e] * time_w[kk] + time_b[kk]);
        A_s[m][256 + kk] = v;
    }

    int n0 = (tid & 31) * 8;
    int m0 = (tid >> 5) * 4;
    float acc[4][8];
    #pragma unroll
    for (int i = 0; i < 4; ++i)
        #pragma unroll
        for (int j = 0; j < 8; ++j) acc[i][j] = 0.f;

    for (int k0 = 0; k0 < KP; k0 += 8) {
        __syncthreads();
        #pragma unroll
        for (int i = 0; i < 8; ++i)
            W_s[i][tid] = Wt[(k0 + i) * 256 + tid];
        __syncthreads();
        #pragma unroll
        for (int kk = 0; kk < 8; ++kk) {
            float4 wa = *(const float4*)&W_s[kk][n0];
            float4 wb = *(const float4*)&W_s[kk][n0 + 4];
            #pragma unroll
            for (int i = 0; i < 4; ++i) {
                float a = A_s[m0 + i][k0 + kk];
                acc[i][0] += a * wa.x; acc[i][1] += a * wa.y;
                acc[i][2] += a * wa.z; acc[i][3] += a * wa.w;
                acc[i][4] += a * wb.x; acc[i][5] += a * wb.y;
                acc[i][6] += a * wb.z; acc[i][7] += a * wb.w;
            }
        }
    }

    #pragma unroll
    for (int i = 0; i < 4; ++i) {
        int e = e0 + m0 + i;
        if (e < E) {
            union { uint4 v; unsigned short u[8]; } pk;
            #pragma unroll
            for (int j = 0; j < 8; ++j) {
                int n = n0 + j;
                float b = (n < 128) ? wk_b[n] : wv_b[n - 128];
                pk.u[j] = bf16_bits(acc[i][j] + b);
            }
            *(uint4*)&KVb[(size_t)e * 256 + n0] = pk.v;
        }
    }
}

// ---- segment offsets via binary search (edge_dst sorted ascending) ----
__global__ void seg_offsets(const int* __restrict__ edge_dst, int* __restrict__ start,
                            int D, int E) {
    int d = blockIdx.x * blockDim.x + threadIdx.x;
    if (d > D) return;
    int lo = 0, hi = E;
    while (lo < hi) {
        int mid = (lo + hi) >> 1;
        if (edge_dst[mid] < d) lo = mid + 1; else hi = mid;
    }
    start[d] = lo;
}

// ---- attention: one 128-thread block per destination, online softmax ----
__global__ __launch_bounds__(128) void attn_kernel(
        const float* __restrict__ Qd, const unsigned short* __restrict__ KVb,
        const int* __restrict__ start, float* __restrict__ h, int D) {
    int d = blockIdx.x;
    if (d >= D) return;
    int o = threadIdx.x; // 0..127, head = o/16
    float q = Qd[(size_t)d * 128 + o];
    int s0 = start[d], s1 = start[d + 1];
    float m = -INFINITY, l = 0.f, acc = 0.f;
    for (int e = s0; e < s1; ++e) {
        float kf = bf16_to_f(KVb[(size_t)e * 256 + o]);
        float vf = bf16_to_f(KVb[(size_t)e * 256 + 128 + o]);
        float qk = q * kf;
        qk += __shfl_xor(qk, 8, 16);
        qk += __shfl_xor(qk, 4, 16);
        qk += __shfl_xor(qk, 2, 16);
        qk += __shfl_xor(qk, 1, 16);
        float s = qk > 0.f ? qk : 0.2f * qk;   // leaky_relu(., 0.2)
        float nm = fmaxf(m, s);
        float sc = __expf(m - nm);
        float p  = __expf(s - nm);
        l   = l * sc + p;
        acc = acc * sc + p * vf;
        m = nm;
    }
    h[(size_t)d * 128 + o] = (l > 0.f) ? acc / l : 0.f;
}

// ---- out = LN(relu([h, q_data] @ wout^T + b)) ----
__global__ __launch_bounds__(512) void out_kernel(
        const float* __restrict__ h, const float* __restrict__ src_feat,
        const int* __restrict__ src_idx,
        const float* __restrict__ wout_w, const float* __restrict__ wout_b,
        const float* __restrict__ ln_g, const float* __restrict__ ln_b,
        float* __restrict__ out, int D) {
    __shared__ float in_s[4][256];
    __shared__ float red1[8], red2[8];
    int tid = threadIdx.x;
    int d0 = blockIdx.x * 4;
    for (int idx = tid; idx < 1024; idx += 512) {
        int r = idx >> 8, c = idx & 255;
        int d = d0 + r;
        float v = 0.f;
        if (d < D) v = (c < 128) ? h[(size_t)d * 128 + c]
                                 : src_feat[(size_t)src_idx[d] * 128 + (c - 128)];
        in_s[r][c] = v;
    }
    __syncthreads();
    int r = tid >> 7, o = tid & 127;
    int d = d0 + r;
    float v = 0.f;
    if (d < D) {
        float accv = wout_b[o];
        const float4* w4 = (const float4*)(wout_w + (size_t)o * 256);
        const float4* i4 = (const float4*)in_s[r];
        #pragma unroll
        for (int c = 0; c < 64; ++c) {
            float4 w = w4[c], x = i4[c];
            accv += x.x * w.x + x.y * w.y + x.z * w.z + x.w * w.w;
        }
        v = fmaxf(accv, 0.f);
    }
    float s1 = v, s2 = v * v;
    #pragma unroll
    for (int off = 32; off; off >>= 1) {
        s1 += __shfl_xor(s1, off);
        s2 += __shfl_xor(s2, off);
    }
    int w = tid >> 6;
    if ((tid & 63) == 0) { red1[w] = s1; red2[w] = s2; }
    __syncthreads();
    if (d < D) {
        float sum1 = red1[2 * r] + red1[2 * r + 1];
        float sum2 = red2[2 * r] + red2[2 * r + 1];
        float mu  = sum1 * (1.f / 128.f);
        float var = sum2 * (1.f / 128.f) - mu * mu;
        float rs  = rsqrtf(var + 1e-5f);
        out[(size_t)d * 128 + o] = (v - mu) * rs * ln_g[o] + ln_b[o];
    }
}

extern "C" void kernel_launch(void* const* d_in, const int* in_sizes, int n_in,
                              void* d_out, int out_size, void* d_ws, size_t ws_size,
                              hipStream_t stream) {
    const float* src_feat = (const float*)d_in[0];
    const float* edge_f   = (const float*)d_in[1];
    const float* edge_dt  = (const float*)d_in[2];
    const float* time_w   = (const float*)d_in[3];
    const float* time_b   = (const float*)d_in[4];
    const float* wq_w     = (const float*)d_in[5];
    const float* wq_b     = (const float*)d_in[6];
    const float* wk_w     = (const float*)d_in[7];
    const float* wk_b     = (const float*)d_in[8];
    const float* wv_w     = (const float*)d_in[9];
    const float* wv_b     = (const float*)d_in[10];
    const float* wout_w   = (const float*)d_in[11];
    const float* wout_b   = (const float*)d_in[12];
    const float* ln_g     = (const float*)d_in[13];
    const float* ln_b     = (const float*)d_in[14];
    const int*   src_idx  = (const int*)d_in[15];
    const int*   edge_dst = (const int*)d_in[16];

    int DE = in_sizes[0] / 128;
    int E  = in_sizes[1] / 128;
    int D  = DE - E;

    char* ws = (char*)d_ws;
    size_t off = 0;
    auto alloc = [&](size_t bytes) {
        void* p = ws + off;
        off = (off + bytes + 511) & ~(size_t)511;
        return p;
    };
    float*          Wt    = (float*)alloc((size_t)KP * 256 * 4);
    float*          cq    = (float*)alloc(128 * 4);
    float*          Qd    = (float*)alloc((size_t)D * 128 * 4);
    unsigned short* KVb   = (unsigned short*)alloc((size_t)E * 256 * 2);
    float*          hb    = (float*)alloc((size_t)D * 128 * 4);
    int*            start = (int*)alloc((size_t)(D + 1) * 4);

    hipLaunchKernelGGL(prep_wt, dim3(KP), dim3(256), 0, stream, wk_w, wv_w, Wt);
    hipLaunchKernelGGL(prep_cq, dim3(1), dim3(128), 0, stream, wq_w, wq_b, time_b, cq);
    hipLaunchKernelGGL(qd_kernel, dim3((D + 3) / 4), dim3(512), 0, stream,
                       src_feat, src_idx, wq_w, cq, Qd, D);
    hipLaunchKernelGGL(kv_gemm, dim3((E + 31) / 32), dim3(256), 0, stream,
                       src_feat, src_idx, edge_f, edge_dt, time_w, time_b,
                       Wt, wk_b, wv_b, KVb, D, E);
    hipLaunchKernelGGL(seg_offsets, dim3((D + 1 + 255) / 256), dim3(256), 0, stream,
                       edge_dst, start, D, E);
    hipLaunchKernelGGL(attn_kernel, dim3(D), dim3(128), 0, stream, Qd, KVb, start, hb, D);
    hipLaunchKernelGGL(out_kernel, dim3((D + 3) / 4), dim3(512), 0, stream,
                       hb, src_feat, src_idx, wout_w, wout_b, ln_g, ln_b, (float*)d_out, D);
}

// Round 2
// 648.655 us; speedup vs baseline: 2.7218x; 2.7218x over previous
//
#include <hip/hip_runtime.h>
#include <stdint.h>

#define DIM_TIME 100
#define DQ 228
#define DKV 356
#define KPAD 384
#define NB 256
#define BM 64
#define BK 32
#define NCHUNK 12
#define A_STRIDE 392   // bf16 elems; 392*2=784 B -> 196 words, %32==4 -> 2-way (free)

typedef short v8s __attribute__((ext_vector_type(8)));
typedef float v4f __attribute__((ext_vector_type(4)));

__device__ __forceinline__ unsigned short bf16_bits(float f) {
    union { float f; uint32_t u; } c; c.f = f;
    uint32_t u = c.u;
    uint32_t r = (u + 0x7FFFu + ((u >> 16) & 1u)) >> 16;
    return (unsigned short)r;
}
__device__ __forceinline__ float bf16_to_f(unsigned short h) {
    union { uint32_t u; float f; } c; c.u = ((uint32_t)h) << 16; return c.f;
}

// ---- prep: Wt2[n][k] bf16, n in [0,256) (K rows then V rows), k padded to 384 ----
__global__ void prep_wt2(const float* __restrict__ wk_w, const float* __restrict__ wv_w,
                         unsigned short* __restrict__ Wt2) {
    int n = blockIdx.x;       // 0..255
    int k = threadIdx.x;      // 0..383
    float v = 0.f;
    if (k < DKV) v = (n < 128) ? wk_w[n * DKV + k] : wv_w[(n - 128) * DKV + k];
    Wt2[n * KPAD + k] = bf16_bits(v);
}

// ---- prep: Wqt[k][o] = wq_w[o][k] for k<128 (f32) ----
__global__ void prep_wqt(const float* __restrict__ wq_w, float* __restrict__ Wqt) {
    int k = blockIdx.x;   // 0..127
    int o = threadIdx.x;  // 0..127
    Wqt[k * 128 + o] = wq_w[o * DQ + k];
}

// ---- prep: Wot[k][o] = wout_w[o][k] (f32), k<256 ----
__global__ void prep_wot(const float* __restrict__ wout_w, float* __restrict__ Wot) {
    int k = blockIdx.x;   // 0..255
    int o = threadIdx.x;  // 0..127
    Wot[k * 128 + o] = wout_w[o * 256 + k];
}

// ---- prep: cq[o] = wq_b[o] + sum_t cos(time_b[t]) * wq_w[o,128+t] ----
__global__ void prep_cq(const float* __restrict__ wq_w, const float* __restrict__ wq_b,
                        const float* __restrict__ time_b, float* __restrict__ cq) {
    int o = threadIdx.x; // 128
    float s = wq_b[o];
    for (int t = 0; t < DIM_TIME; ++t)
        s += cosf(time_b[t]) * wq_w[o * DQ + 128 + t];
    cq[o] = s;
}

// ---- Qd: 64 threads, 8 rows/block, transposed-weight coalesced loads ----
__global__ __launch_bounds__(64) void qd_kernel(
        const float* __restrict__ src_feat, const int* __restrict__ src_idx,
        const float* __restrict__ Wqt, const float* __restrict__ cq,
        float* __restrict__ Qd, int D) {
    __shared__ float q_s[8][128];
    int o = threadIdx.x;
    int d0 = blockIdx.x * 8;
    #pragma unroll
    for (int i = 0; i < 8; ++i) {
        int d = d0 + i;
        float v0 = 0.f, v1 = 0.f;
        if (d < D) {
            const float* p = src_feat + (size_t)src_idx[d] * 128;
            v0 = p[o]; v1 = p[o + 64];
        }
        q_s[i][o] = v0; q_s[i][o + 64] = v1;
    }
    __syncthreads();
    float c0 = cq[o], c1 = cq[o + 64];
    float acc0[8], acc1[8];
    #pragma unroll
    for (int i = 0; i < 8; ++i) { acc0[i] = c0; acc1[i] = c1; }
    #pragma unroll 4
    for (int k = 0; k < 128; ++k) {
        float w0 = Wqt[k * 128 + o];
        float w1 = Wqt[k * 128 + 64 + o];
        #pragma unroll
        for (int i = 0; i < 8; ++i) {
            float a = q_s[i][k];
            acc0[i] += a * w0; acc1[i] += a * w1;
        }
    }
    #pragma unroll
    for (int i = 0; i < 8; ++i) {
        int d = d0 + i;
        if (d < D) {
            Qd[(size_t)d * 128 + o]      = acc0[i];
            Qd[(size_t)d * 128 + 64 + o] = acc1[i];
        }
    }
}

// ---- KV GEMM via MFMA: C[e][0:128]=K, C[e][128:256]=V, bf16 out ----
// 256 threads = 4 waves; wave tile 64(m) x 64(n); A in LDS, B frags from global (L2).
__global__ __launch_bounds__(256) void kv_mfma(
        const float* __restrict__ src_feat, const int* __restrict__ src_idx,
        const float* __restrict__ edge_f, const float* __restrict__ edge_dt,
        const float* __restrict__ time_w, const float* __restrict__ time_b,
        const unsigned short* __restrict__ Wt2,
        const float* __restrict__ wk_b, const float* __restrict__ wv_b,
        unsigned short* __restrict__ KVb, int D, int E) {
    __shared__ unsigned short A_s[BM * A_STRIDE];   // 50176 B
    int tid = threadIdx.x;
    int e0 = blockIdx.x * BM;
    int lane = tid & 63;
    int wave = tid >> 6;
    int l15 = lane & 15, quad = lane >> 4;
    int wn = wave * 64;

    // ---- build A tile (bf16) ----
    {
        int row = tid >> 2;          // 0..63
        int cb  = (tid & 3) * 8;     // float4-group base
        int e = e0 + row;
        bool ok = (e < E);
        size_t nbase = ok ? (size_t)src_idx[D + e] * 128 : 0;
        #pragma unroll
        for (int i = 0; i < 8; ++i) {
            int c4 = cb + i;
            float4 v = ok ? *(const float4*)(src_feat + nbase + c4 * 4)
                          : make_float4(0.f, 0.f, 0.f, 0.f);
            ushort4 w;
            w.x = bf16_bits(v.x); w.y = bf16_bits(v.y);
            w.z = bf16_bits(v.z); w.w = bf16_bits(v.w);
            *(ushort4*)&A_s[row * A_STRIDE + c4 * 4] = w;
        }
        #pragma unroll
        for (int i = 0; i < 8; ++i) {
            int c4 = cb + i;
            float4 v = ok ? *(const float4*)(edge_f + (size_t)e * 128 + c4 * 4)
                          : make_float4(0.f, 0.f, 0.f, 0.f);
            ushort4 w;
            w.x = bf16_bits(v.x); w.y = bf16_bits(v.y);
            w.z = bf16_bits(v.z); w.w = bf16_bits(v.w);
            *(ushort4*)&A_s[row * A_STRIDE + 128 + c4 * 4] = w;
        }
    }
    {   // time cols 256..383 (cos for c<100, zeros beyond)
        int c = tid & 127;
        int rbase = tid >> 7;        // 0 or 1
        bool vc = (c < DIM_TIME);
        float tw = vc ? time_w[c] : 0.f;
        float tb = vc ? time_b[c] : 0.f;
        #pragma unroll
        for (int i = 0; i < 32; ++i) {
            int row = i * 2 + rbase;
            int e = e0 + row;
            float v = 0.f;
            if (vc && e < E) v = __cosf(edge_dt[e] * tw + tb);
            A_s[row * A_STRIDE + 256 + c] = bf16_bits(v);
        }
    }
    __syncthreads();

    v4f acc[4][4];
    #pragma unroll
    for (int mf = 0; mf < 4; ++mf)
        #pragma unroll
        for (int nf = 0; nf < 4; ++nf)
            acc[mf][nf] = (v4f)(0.f);

    for (int ch = 0; ch < NCHUNK; ++ch) {
        v8s afrag[4], bfrag[4];
        #pragma unroll
        for (int nf = 0; nf < 4; ++nf)
            bfrag[nf] = *(const v8s*)(Wt2 + (size_t)(wn + nf * 16 + l15) * KPAD
                                      + ch * BK + quad * 8);
        #pragma unroll
        for (int mf = 0; mf < 4; ++mf)
            afrag[mf] = *(const v8s*)&A_s[(mf * 16 + l15) * A_STRIDE + ch * BK + quad * 8];
        #pragma unroll
        for (int mf = 0; mf < 4; ++mf)
            #pragma unroll
            for (int nf = 0; nf < 4; ++nf)
                acc[mf][nf] = __builtin_amdgcn_mfma_f32_16x16x32_bf16(
                                  afrag[mf], bfrag[nf], acc[mf][nf], 0, 0, 0);
    }

    // epilogue: +bias, bf16 store. C/D: col=lane&15, row=quad*4+r
    #pragma unroll
    for (int nf = 0; nf < 4; ++nf) {
        int n = wn + nf * 16 + l15;
        float bias = (n < 128) ? wk_b[n] : wv_b[n - 128];
        #pragma unroll
        for (int mf = 0; mf < 4; ++mf) {
            #pragma unroll
            for (int r = 0; r < 4; ++r) {
                int e = e0 + mf * 16 + quad * 4 + r;
                if (e < E)
                    KVb[(size_t)e * NB + n] = bf16_bits(acc[mf][nf][r] + bias);
            }
        }
    }
}

// ---- segment offsets (edge_dst sorted) ----
__global__ void seg_offsets(const int* __restrict__ edge_dst, int* __restrict__ start,
                            int D, int E) {
    int d = blockIdx.x * blockDim.x + threadIdx.x;
    if (d > D) return;
    int lo = 0, hi = E;
    while (lo < hi) {
        int mid = (lo + hi) >> 1;
        if (edge_dst[mid] < d) lo = mid + 1; else hi = mid;
    }
    start[d] = lo;
}

// ---- attention: one 128-thread block per destination, online softmax ----
__global__ __launch_bounds__(128) void attn_kernel(
        const float* __restrict__ Qd, const unsigned short* __restrict__ KVb,
        const int* __restrict__ start, float* __restrict__ h, int D) {
    int d = blockIdx.x;
    if (d >= D) return;
    int o = threadIdx.x;
    float q = Qd[(size_t)d * 128 + o];
    int s0 = start[d], s1 = start[d + 1];
    float m = -INFINITY, l = 0.f, acc = 0.f;
    for (int e = s0; e < s1; ++e) {
        float kf = bf16_to_f(KVb[(size_t)e * 256 + o]);
        float vf = bf16_to_f(KVb[(size_t)e * 256 + 128 + o]);
        float qk = q * kf;
        qk += __shfl_xor(qk, 8, 16);
        qk += __shfl_xor(qk, 4, 16);
        qk += __shfl_xor(qk, 2, 16);
        qk += __shfl_xor(qk, 1, 16);
        float s = qk > 0.f ? qk : 0.2f * qk;
        float nm = fmaxf(m, s);
        float sc = __expf(m - nm);
        float p  = __expf(s - nm);
        l   = l * sc + p;
        acc = acc * sc + p * vf;
        m = nm;
    }
    h[(size_t)d * 128 + o] = (l > 0.f) ? acc / l : 0.f;
}

// ---- out = LN(relu([h, q_data] @ wout^T + b)) : 64 threads, 8 rows/block ----
__global__ __launch_bounds__(64) void out_kernel(
        const float* __restrict__ h, const float* __restrict__ src_feat,
        const int* __restrict__ src_idx, const float* __restrict__ Wot,
        const float* __restrict__ wout_b, const float* __restrict__ ln_g,
        const float* __restrict__ ln_b, float* __restrict__ out, int D) {
    __shared__ float in_s[8][256];
    int o = threadIdx.x;
    int d0 = blockIdx.x * 8;
    #pragma unroll
    for (int i = 0; i < 8; ++i) {
        int d = d0 + i;
        float a0 = 0.f, a1 = 0.f, b0 = 0.f, b1 = 0.f;
        if (d < D) {
            const float* ph = h + (size_t)d * 128;
            a0 = ph[o]; a1 = ph[o + 64];
            const float* pf = src_feat + (size_t)src_idx[d] * 128;
            b0 = pf[o]; b1 = pf[o + 64];
        }
        in_s[i][o] = a0; in_s[i][o + 64] = a1;
        in_s[i][128 + o] = b0; in_s[i][192 + o] = b1;
    }
    __syncthreads();
    float bb0 = wout_b[o], bb1 = wout_b[o + 64];
    float acc0[8], acc1[8];
    #pragma unroll
    for (int i = 0; i < 8; ++i) { acc0[i] = bb0; acc1[i] = bb1; }
    #pragma unroll 4
    for (int k = 0; k < 256; ++k) {
        float w0 = Wot[k * 128 + o];
        float w1 = Wot[k * 128 + 64 + o];
        #pragma unroll
        for (int i = 0; i < 8; ++i) {
            float a = in_s[i][k];
            acc0[i] += a * w0; acc1[i] += a * w1;
        }
    }
    float g0 = ln_g[o], g1 = ln_g[o + 64];
    float lb0 = ln_b[o], lb1 = ln_b[o + 64];
    #pragma unroll
    for (int i = 0; i < 8; ++i) {
        float v0 = fmaxf(acc0[i], 0.f), v1 = fmaxf(acc1[i], 0.f);
        float s1 = v0 + v1, s2 = v0 * v0 + v1 * v1;
        #pragma unroll
        for (int off = 32; off; off >>= 1) {
            s1 += __shfl_xor(s1, off);
            s2 += __shfl_xor(s2, off);
        }
        float mu  = s1 * (1.f / 128.f);
        float var = s2 * (1.f / 128.f) - mu * mu;
        float rs  = rsqrtf(var + 1e-5f);
        int d = d0 + i;
        if (d < D) {
            out[(size_t)d * 128 + o]      = (v0 - mu) * rs * g0 + lb0;
            out[(size_t)d * 128 + 64 + o] = (v1 - mu) * rs * g1 + lb1;
        }
    }
}

extern "C" void kernel_launch(void* const* d_in, const int* in_sizes, int n_in,
                              void* d_out, int out_size, void* d_ws, size_t ws_size,
                              hipStream_t stream) {
    const float* src_feat = (const float*)d_in[0];
    const float* edge_f   = (const float*)d_in[1];
    const float* edge_dt  = (const float*)d_in[2];
    const float* time_w   = (const float*)d_in[3];
    const float* time_b   = (const float*)d_in[4];
    const float* wq_w     = (const float*)d_in[5];
    const float* wq_b     = (const float*)d_in[6];
    const float* wk_w     = (const float*)d_in[7];
    const float* wk_b     = (const float*)d_in[8];
    const float* wv_w     = (const float*)d_in[9];
    const float* wv_b     = (const float*)d_in[10];
    const float* wout_w   = (const float*)d_in[11];
    const float* wout_b   = (const float*)d_in[12];
    const float* ln_g     = (const float*)d_in[13];
    const float* ln_b     = (const float*)d_in[14];
    const int*   src_idx  = (const int*)d_in[15];
    const int*   edge_dst = (const int*)d_in[16];

    int DE = in_sizes[0] / 128;
    int E  = in_sizes[1] / 128;
    int D  = DE - E;

    char* ws = (char*)d_ws;
    size_t off = 0;
    auto alloc = [&](size_t bytes) {
        void* p = ws + off;
        off = (off + bytes + 511) & ~(size_t)511;
        return p;
    };
    unsigned short* Wt2   = (unsigned short*)alloc((size_t)NB * KPAD * 2);
    float*          Wqt   = (float*)alloc(128 * 128 * 4);
    float*          Wot   = (float*)alloc(256 * 128 * 4);
    float*          cq    = (float*)alloc(128 * 4);
    float*          Qd    = (float*)alloc((size_t)D * 128 * 4);
    unsigned short* KVb   = (unsigned short*)alloc((size_t)E * 256 * 2);
    float*          hb    = (float*)alloc((size_t)D * 128 * 4);
    int*            start = (int*)alloc((size_t)(D + 1) * 4);

    hipLaunchKernelGGL(prep_wt2, dim3(NB), dim3(KPAD), 0, stream, wk_w, wv_w, Wt2);
    hipLaunchKernelGGL(prep_wqt, dim3(128), dim3(128), 0, stream, wq_w, Wqt);
    hipLaunchKernelGGL(prep_wot, dim3(256), dim3(128), 0, stream, wout_w, Wot);
    hipLaunchKernelGGL(prep_cq, dim3(1), dim3(128), 0, stream, wq_w, wq_b, time_b, cq);
    hipLaunchKernelGGL(qd_kernel, dim3((D + 7) / 8), dim3(64), 0, stream,
                       src_feat, src_idx, Wqt, cq, Qd, D);
    hipLaunchKernelGGL(kv_mfma, dim3((E + BM - 1) / BM), dim3(256), 0, stream,
                       src_feat, src_idx, edge_f, edge_dt, time_w, time_b,
                       Wt2, wk_b, wv_b, KVb, D, E);
    hipLaunchKernelGGL(seg_offsets, dim3((D + 1 + 255) / 256), dim3(256), 0, stream,
                       edge_dst, start, D, E);
    hipLaunchKernelGGL(attn_kernel, dim3(D), dim3(128), 0, stream, Qd, KVb, start, hb, D);
    hipLaunchKernelGGL(out_kernel, dim3((D + 7) / 8), dim3(64), 0, stream,
                       hb, src_feat, src_idx, Wot, wout_b, ln_g, ln_b, (float*)d_out, D);
}

// Round 3
// 639.980 us; speedup vs baseline: 2.7587x; 1.0136x over previous
//
#include <hip/hip_runtime.h>
#include <stdint.h>

#define DIM_TIME 100
#define DQ 228
#define DKV 356
#define KPAD 384
#define NB 256
#define BM 64
#define BK 32
#define NCHUNK 12
#define A_STRIDE 392   // bf16 elems
#define C_STRIDE 264   // bf16 elems, epilogue staging

typedef short v8s __attribute__((ext_vector_type(8)));
typedef float v4f __attribute__((ext_vector_type(4)));

__device__ __forceinline__ unsigned short bf16_bits(float f) {
    union { float f; uint32_t u; } c; c.f = f;
    uint32_t u = c.u;
    uint32_t r = (u + 0x7FFFu + ((u >> 16) & 1u)) >> 16;
    return (unsigned short)r;
}
__device__ __forceinline__ float bf16_lo(uint32_t u) {
    union { uint32_t u; float f; } c; c.u = u << 16; return c.f;
}
__device__ __forceinline__ float bf16_hi(uint32_t u) {
    union { uint32_t u; float f; } c; c.u = u & 0xFFFF0000u; return c.f;
}

// ---- prep: Wt2[n][k] bf16, n in [0,256) (K rows then V rows), k padded to 384 ----
__global__ void prep_wt2(const float* __restrict__ wk_w, const float* __restrict__ wv_w,
                         unsigned short* __restrict__ Wt2) {
    int n = blockIdx.x;       // 0..255
    int k = threadIdx.x;      // 0..383
    float v = 0.f;
    if (k < DKV) v = (n < 128) ? wk_w[n * DKV + k] : wv_w[(n - 128) * DKV + k];
    Wt2[n * KPAD + k] = bf16_bits(v);
}

// ---- prep: Wqt[k][o] = wq_w[o][k] for k<128 (f32) ----
__global__ void prep_wqt(const float* __restrict__ wq_w, float* __restrict__ Wqt) {
    int k = blockIdx.x, o = threadIdx.x;
    Wqt[k * 128 + o] = wq_w[o * DQ + k];
}

// ---- prep: Wot[k][o] = wout_w[o][k] (f32), k<256 ----
__global__ void prep_wot(const float* __restrict__ wout_w, float* __restrict__ Wot) {
    int k = blockIdx.x, o = threadIdx.x;
    Wot[k * 128 + o] = wout_w[o * 256 + k];
}

// ---- prep: cq[o] = wq_b[o] + sum_t cos(time_b[t]) * wq_w[o,128+t] ----
__global__ void prep_cq(const float* __restrict__ wq_w, const float* __restrict__ wq_b,
                        const float* __restrict__ time_b, float* __restrict__ cq) {
    int o = threadIdx.x;
    float s = wq_b[o];
    for (int t = 0; t < DIM_TIME; ++t)
        s += cosf(time_b[t]) * wq_w[o * DQ + 128 + t];
    cq[o] = s;
}

// ---- Qd: 256 threads = 4 waves x 8 rows, wave-private (no barriers) ----
__global__ __launch_bounds__(256) void qd_kernel(
        const float* __restrict__ src_feat, const int* __restrict__ src_idx,
        const float* __restrict__ Wqt, const float* __restrict__ cq,
        float* __restrict__ Qd, int D) {
    __shared__ float q_s[32][128];
    int lane = threadIdx.x & 63, wave = threadIdx.x >> 6;
    int r0 = wave * 8;
    int d0 = blockIdx.x * 32 + r0;
    #pragma unroll
    for (int i = 0; i < 8; ++i) {
        int d = d0 + i;
        float v0 = 0.f, v1 = 0.f;
        if (d < D) {
            const float* p = src_feat + (size_t)src_idx[d] * 128;
            v0 = p[lane]; v1 = p[lane + 64];
        }
        q_s[r0 + i][lane] = v0; q_s[r0 + i][lane + 64] = v1;
    }
    float c0 = cq[lane], c1 = cq[lane + 64];
    float acc0[8], acc1[8];
    #pragma unroll
    for (int i = 0; i < 8; ++i) { acc0[i] = c0; acc1[i] = c1; }
    #pragma unroll 8
    for (int k = 0; k < 128; ++k) {
        float w0 = Wqt[k * 128 + lane];
        float w1 = Wqt[k * 128 + 64 + lane];
        #pragma unroll
        for (int i = 0; i < 8; ++i) {
            float a = q_s[r0 + i][k];
            acc0[i] += a * w0; acc1[i] += a * w1;
        }
    }
    #pragma unroll
    for (int i = 0; i < 8; ++i) {
        int d = d0 + i;
        if (d < D) {
            Qd[(size_t)d * 128 + lane]      = acc0[i];
            Qd[(size_t)d * 128 + 64 + lane] = acc1[i];
        }
    }
}

// ---- KV GEMM via MFMA, register double-buffered frags, LDS-staged epilogue ----
__global__ __launch_bounds__(256) void kv_mfma(
        const float* __restrict__ src_feat, const int* __restrict__ src_idx,
        const float* __restrict__ edge_f, const float* __restrict__ edge_dt,
        const float* __restrict__ time_w, const float* __restrict__ time_b,
        const unsigned short* __restrict__ Wt2,
        const float* __restrict__ wk_b, const float* __restrict__ wv_b,
        unsigned short* __restrict__ KVb, int D, int E) {
    __shared__ unsigned short A_s[BM * A_STRIDE];   // 50176 B
    int tid = threadIdx.x;
    int e0 = blockIdx.x * BM;
    int lane = tid & 63, wave = tid >> 6;
    int l15 = lane & 15, quad = lane >> 4;
    int wn = wave * 64;

    // ---- build A tile (bf16) ----
    {
        int row = tid >> 2;          // 0..63
        int cb  = (tid & 3) * 8;
        int e = e0 + row;
        bool ok = (e < E);
        size_t nbase = ok ? (size_t)src_idx[D + e] * 128 : 0;
        #pragma unroll
        for (int i = 0; i < 8; ++i) {
            int c4 = cb + i;
            float4 v = ok ? *(const float4*)(src_feat + nbase + c4 * 4)
                          : make_float4(0.f, 0.f, 0.f, 0.f);
            ushort4 w;
            w.x = bf16_bits(v.x); w.y = bf16_bits(v.y);
            w.z = bf16_bits(v.z); w.w = bf16_bits(v.w);
            *(ushort4*)&A_s[row * A_STRIDE + c4 * 4] = w;
        }
        #pragma unroll
        for (int i = 0; i < 8; ++i) {
            int c4 = cb + i;
            float4 v = ok ? *(const float4*)(edge_f + (size_t)e * 128 + c4 * 4)
                          : make_float4(0.f, 0.f, 0.f, 0.f);
            ushort4 w;
            w.x = bf16_bits(v.x); w.y = bf16_bits(v.y);
            w.z = bf16_bits(v.z); w.w = bf16_bits(v.w);
            *(ushort4*)&A_s[row * A_STRIDE + 128 + c4 * 4] = w;
        }
    }
    {   // time cols 256..383
        int c = tid & 127;
        int rbase = tid >> 7;
        bool vc = (c < DIM_TIME);
        float tw = vc ? time_w[c] : 0.f;
        float tb = vc ? time_b[c] : 0.f;
        #pragma unroll
        for (int i = 0; i < 32; ++i) {
            int row = i * 2 + rbase;
            int e = e0 + row;
            float v = 0.f;
            if (vc && e < E) v = __cosf(edge_dt[e] * tw + tb);
            A_s[row * A_STRIDE + 256 + c] = bf16_bits(v);
        }
    }
    __syncthreads();

    v4f acc[4][4];
    #pragma unroll
    for (int mf = 0; mf < 4; ++mf)
        #pragma unroll
        for (int nf = 0; nf < 4; ++nf)
            acc[mf][nf] = (v4f)(0.f);

    const unsigned short* wp = Wt2 + (size_t)(wn + l15) * KPAD + quad * 8;
    const unsigned short* ap = A_s + l15 * A_STRIDE + quad * 8;

    v8s bcur[4], acur[4];
    #pragma unroll
    for (int nf = 0; nf < 4; ++nf) bcur[nf] = *(const v8s*)(wp + nf * 16 * KPAD);
    #pragma unroll
    for (int mf = 0; mf < 4; ++mf) acur[mf] = *(const v8s*)(ap + mf * 16 * A_STRIDE);

    #pragma unroll 2
    for (int ch = 0; ch < NCHUNK; ++ch) {
        int k2 = (ch + 1 < NCHUNK) ? (ch + 1) * BK : 0;
        v8s bn[4], an[4];
        #pragma unroll
        for (int nf = 0; nf < 4; ++nf) bn[nf] = *(const v8s*)(wp + nf * 16 * KPAD + k2);
        #pragma unroll
        for (int mf = 0; mf < 4; ++mf) an[mf] = *(const v8s*)(ap + mf * 16 * A_STRIDE + k2);
        #pragma unroll
        for (int mf = 0; mf < 4; ++mf)
            #pragma unroll
            for (int nf = 0; nf < 4; ++nf)
                acc[mf][nf] = __builtin_amdgcn_mfma_f32_16x16x32_bf16(
                                  acur[mf], bcur[nf], acc[mf][nf], 0, 0, 0);
        #pragma unroll
        for (int nf = 0; nf < 4; ++nf) bcur[nf] = bn[nf];
        #pragma unroll
        for (int mf = 0; mf < 4; ++mf) acur[mf] = an[mf];
    }

    // ---- epilogue: stage C in LDS (reuse A_s), then linear coalesced stores ----
    __syncthreads();
    #pragma unroll
    for (int nf = 0; nf < 4; ++nf) {
        int n = wn + nf * 16 + l15;
        float bias = (n < 128) ? wk_b[n] : wv_b[n - 128];
        #pragma unroll
        for (int mf = 0; mf < 4; ++mf)
            #pragma unroll
            for (int r = 0; r < 4; ++r)
                A_s[(mf * 16 + quad * 4 + r) * C_STRIDE + n] =
                    bf16_bits(acc[mf][nf][r] + bias);
    }
    __syncthreads();
    #pragma unroll
    for (int j = 0; j < 8; ++j) {
        int c = j * 256 + tid;          // 0..2047 chunks of 8 ushorts
        int row = c >> 5;
        int col = (c & 31) * 8;
        if (e0 + row < E) {
            v8s v = *(const v8s*)&A_s[row * C_STRIDE + col];
            *(v8s*)&KVb[(size_t)(e0 + row) * NB + col] = v;
        }
    }
}

// ---- segment offsets (edge_dst sorted) ----
__global__ void seg_offsets(const int* __restrict__ edge_dst, int* __restrict__ start,
                            int D, int E) {
    int d = blockIdx.x * blockDim.x + threadIdx.x;
    if (d > D) return;
    int lo = 0, hi = E;
    while (lo < hi) {
        int mid = (lo + hi) >> 1;
        if (edge_dst[mid] < d) lo = mid + 1; else hi = mid;
    }
    start[d] = lo;
}

// ---- attention: 4 waves/block, each wave 4 consecutive dsts, 2 outputs/lane ----
__global__ __launch_bounds__(256) void attn_kernel(
        const float* __restrict__ Qd, const unsigned short* __restrict__ KVb,
        const int* __restrict__ start, float* __restrict__ h, int D) {
    int lane = threadIdx.x & 63, wave = threadIdx.x >> 6;
    int dbase = blockIdx.x * 16 + wave * 4;
    for (int i = 0; i < 4; ++i) {
        int d = dbase + i;
        if (d >= D) break;
        float2 q = *(const float2*)(Qd + (size_t)d * 128 + lane * 2);
        int s0 = start[d], s1 = start[d + 1];
        float m = -INFINITY, l = 0.f, a0 = 0.f, a1 = 0.f;
        for (int e = s0; e < s1; ++e) {
            const unsigned short* kv = KVb + (size_t)e * 256 + lane * 2;
            uint32_t ku = *(const uint32_t*)kv;
            uint32_t vu = *(const uint32_t*)(kv + 128);
            float qk = q.x * bf16_lo(ku) + q.y * bf16_hi(ku);
            qk += __shfl_xor(qk, 4, 8);
            qk += __shfl_xor(qk, 2, 8);
            qk += __shfl_xor(qk, 1, 8);
            float s = qk > 0.f ? qk : 0.2f * qk;   // leaky_relu(., 0.2)
            float nm = fmaxf(m, s);
            float sc = __expf(m - nm);
            float p  = __expf(s - nm);
            l  = l  * sc + p;
            a0 = a0 * sc + p * bf16_lo(vu);
            a1 = a1 * sc + p * bf16_hi(vu);
            m = nm;
        }
        float inv = (l > 0.f) ? 1.f / l : 0.f;
        *(float2*)(h + (size_t)d * 128 + lane * 2) = make_float2(a0 * inv, a1 * inv);
    }
}

// ---- out = LN(relu([h, q_data] @ wout^T + b)) : 4 waves x 8 rows, wave-private ----
__global__ __launch_bounds__(256) void out_kernel(
        const float* __restrict__ h, const float* __restrict__ src_feat,
        const int* __restrict__ src_idx, const float* __restrict__ Wot,
        const float* __restrict__ wout_b, const float* __restrict__ ln_g,
        const float* __restrict__ ln_b, float* __restrict__ out, int D) {
    __shared__ float in_s[32][256];
    int lane = threadIdx.x & 63, wave = threadIdx.x >> 6;
    int r0 = wave * 8;
    int d0 = blockIdx.x * 32 + r0;
    #pragma unroll
    for (int i = 0; i < 8; ++i) {
        int d = d0 + i;
        float a0 = 0.f, a1 = 0.f, b0 = 0.f, b1 = 0.f;
        if (d < D) {
            const float* ph = h + (size_t)d * 128;
            a0 = ph[lane]; a1 = ph[lane + 64];
            const float* pf = src_feat + (size_t)src_idx[d] * 128;
            b0 = pf[lane]; b1 = pf[lane + 64];
        }
        in_s[r0 + i][lane] = a0; in_s[r0 + i][lane + 64] = a1;
        in_s[r0 + i][128 + lane] = b0; in_s[r0 + i][192 + lane] = b1;
    }
    float bb0 = wout_b[lane], bb1 = wout_b[lane + 64];
    float acc0[8], acc1[8];
    #pragma unroll
    for (int i = 0; i < 8; ++i) { acc0[i] = bb0; acc1[i] = bb1; }
    #pragma unroll 8
    for (int k = 0; k < 256; ++k) {
        float w0 = Wot[k * 128 + lane];
        float w1 = Wot[k * 128 + 64 + lane];
        #pragma unroll
        for (int i = 0; i < 8; ++i) {
            float a = in_s[r0 + i][k];
            acc0[i] += a * w0; acc1[i] += a * w1;
        }
    }
    float g0 = ln_g[lane], g1 = ln_g[lane + 64];
    float lb0 = ln_b[lane], lb1 = ln_b[lane + 64];
    #pragma unroll
    for (int i = 0; i < 8; ++i) {
        float v0 = fmaxf(acc0[i], 0.f), v1 = fmaxf(acc1[i], 0.f);
        float s1 = v0 + v1, s2 = v0 * v0 + v1 * v1;
        #pragma unroll
        for (int off = 32; off; off >>= 1) {
            s1 += __shfl_xor(s1, off);
            s2 += __shfl_xor(s2, off);
        }
        float mu  = s1 * (1.f / 128.f);
        float var = s2 * (1.f / 128.f) - mu * mu;
        float rs  = rsqrtf(var + 1e-5f);
        int d = d0 + i;
        if (d < D) {
            out[(size_t)d * 128 + lane]      = (v0 - mu) * rs * g0 + lb0;
            out[(size_t)d * 128 + 64 + lane] = (v1 - mu) * rs * g1 + lb1;
        }
    }
}

extern "C" void kernel_launch(void* const* d_in, const int* in_sizes, int n_in,
                              void* d_out, int out_size, void* d_ws, size_t ws_size,
                              hipStream_t stream) {
    const float* src_feat = (const float*)d_in[0];
    const float* edge_f   = (const float*)d_in[1];
    const float* edge_dt  = (const float*)d_in[2];
    const float* time_w   = (const float*)d_in[3];
    const float* time_b   = (const float*)d_in[4];
    const float* wq_w     = (const float*)d_in[5];
    const float* wq_b     = (const float*)d_in[6];
    const float* wk_w     = (const float*)d_in[7];
    const float* wk_b     = (const float*)d_in[8];
    const float* wv_w     = (const float*)d_in[9];
    const float* wv_b     = (const float*)d_in[10];
    const float* wout_w   = (const float*)d_in[11];
    const float* wout_b   = (const float*)d_in[12];
    const float* ln_g     = (const float*)d_in[13];
    const float* ln_b     = (const float*)d_in[14];
    const int*   src_idx  = (const int*)d_in[15];
    const int*   edge_dst = (const int*)d_in[16];

    int DE = in_sizes[0] / 128;
    int E  = in_sizes[1] / 128;
    int D  = DE - E;

    char* ws = (char*)d_ws;
    size_t off = 0;
    auto alloc = [&](size_t bytes) {
        void* p = ws + off;
        off = (off + bytes + 511) & ~(size_t)511;
        return p;
    };
    unsigned short* Wt2   = (unsigned short*)alloc((size_t)NB * KPAD * 2);
    float*          Wqt   = (float*)alloc(128 * 128 * 4);
    float*          Wot   = (float*)alloc(256 * 128 * 4);
    float*          cq    = (float*)alloc(128 * 4);
    float*          Qd    = (float*)alloc((size_t)D * 128 * 4);
    unsigned short* KVb   = (unsigned short*)alloc((size_t)E * 256 * 2);
    float*          hb    = (float*)alloc((size_t)D * 128 * 4);
    int*            start = (int*)alloc((size_t)(D + 1) * 4);

    hipLaunchKernelGGL(prep_wt2, dim3(NB), dim3(KPAD), 0, stream, wk_w, wv_w, Wt2);
    hipLaunchKernelGGL(prep_wqt, dim3(128), dim3(128), 0, stream, wq_w, Wqt);
    hipLaunchKernelGGL(prep_wot, dim3(256), dim3(128), 0, stream, wout_w, Wot);
    hipLaunchKernelGGL(prep_cq, dim3(1), dim3(128), 0, stream, wq_w, wq_b, time_b, cq);
    hipLaunchKernelGGL(qd_kernel, dim3((D + 31) / 32), dim3(256), 0, stream,
                       src_feat, src_idx, Wqt, cq, Qd, D);
    hipLaunchKernelGGL(kv_mfma, dim3((E + BM - 1) / BM), dim3(256), 0, stream,
                       src_feat, src_idx, edge_f, edge_dt, time_w, time_b,
                       Wt2, wk_b, wv_b, KVb, D, E);
    hipLaunchKernelGGL(seg_offsets, dim3((D + 1 + 255) / 256), dim3(256), 0, stream,
                       edge_dst, start, D, E);
    hipLaunchKernelGGL(attn_kernel, dim3((D + 15) / 16), dim3(256), 0, stream,
                       Qd, KVb, start, hb, D);
    hipLaunchKernelGGL(out_kernel, dim3((D + 31) / 32), dim3(256), 0, stream,
                       hb, src_feat, src_idx, Wot, wout_b, ln_g, ln_b, (float*)d_out, D);
}